// Round 5
// baseline (980.434 us; speedup 1.0000x reference)
//
#include <hip/hip_runtime.h>
#include <hip/hip_bf16.h>
#include <math.h>

#define TT 8192
#define HD 1024
#define FHD 4096
#define NE 8
#define TMAX 72

typedef short s16x8 __attribute__((ext_vector_type(8)));
typedef float f32x4 __attribute__((ext_vector_type(4)));
using bf16 = __hip_bfloat16;
typedef unsigned int u32;

// workspace layout (bytes)
#define OFF_COUNTS 0
#define OFF_CURSOR 64
#define OFF_OFFS   128
#define OFF_E0     256
#define OFF_E1     (OFF_E0 + 4*TT)
#define OFF_W0     (OFF_E1 + 4*TT)
#define OFF_W1     (OFF_W0 + 4*TT)
#define OFF_S0     (OFF_W1 + 4*TT)
#define OFF_S1     (OFF_S0 + 4*TT)
#define OFF_TID    (OFF_S1 + 4*TT)
#define OFF_TW     (OFF_TID + 8*TT)
#define OFF_TMR    (OFF_TW + 8*TT)
#define OFF_TME    (OFF_TMR + 4*144)
#define OFF_TMN    (OFF_TME + 4*144)
#define OFF_XBF    (OFF_TMN + 64)
#define OFF_W1T    (OFF_XBF + 2*TT*HD)
#define OFF_W2T    (OFF_W1T + 2*NE*HD*FHD)
#define OFF_HMID   (OFF_W2T + 2*NE*HD*FHD)
#define OFF_YS     (OFF_HMID + (size_t)2*(2*TT)*FHD)
// ysB aliases the (dead-after-gemm1) w1t region

__device__ __forceinline__ void gload_lds16(const void* g, void* l) {
    __builtin_amdgcn_global_load_lds(
        (const __attribute__((address_space(1))) u32*)g,
        (__attribute__((address_space(3))) u32*)l, 16, 0, 0);
}

__global__ __launch_bounds__(256) void cast_x_kernel(const float* __restrict__ x, bf16* __restrict__ xbf) {
    int i = (blockIdx.x * 256 + threadIdx.x) * 8;
    float4 a = *reinterpret_cast<const float4*>(&x[i]);
    float4 b = *reinterpret_cast<const float4*>(&x[i + 4]);
    bf16 h[8];
    h[0] = __float2bfloat16(a.x); h[1] = __float2bfloat16(a.y);
    h[2] = __float2bfloat16(a.z); h[3] = __float2bfloat16(a.w);
    h[4] = __float2bfloat16(b.x); h[5] = __float2bfloat16(b.y);
    h[6] = __float2bfloat16(b.z); h[7] = __float2bfloat16(b.w);
    *reinterpret_cast<uint4*>(&xbf[i]) = *reinterpret_cast<uint4*>(h);
}

// transpose+cast: out[c][r] = bf16(in[r][c]); per-expert matrices of shape [R][C].
__global__ __launch_bounds__(256) void transpose_cast_kernel(const float* __restrict__ in,
        bf16* __restrict__ out, int R, int C) {
    __shared__ float tile[64][65];
    int rt = R >> 6, ct = C >> 6;
    int e = blockIdx.x / (rt * ct);
    int rem = blockIdx.x % (rt * ct);
    int r0 = (rem / ct) << 6, c0 = (rem % ct) << 6;
    const float* ine = in + (size_t)e * R * C;
    bf16* oute = out + (size_t)e * R * C;
    int tid = threadIdx.x;
#pragma unroll
    for (int i = 0; i < 4; ++i) {
        int lin = tid + i * 256;
        int r = lin >> 4, cg = lin & 15;
        float4 v = *reinterpret_cast<const float4*>(&ine[(size_t)(r0 + r) * C + c0 + cg * 4]);
        tile[r][cg * 4 + 0] = v.x; tile[r][cg * 4 + 1] = v.y;
        tile[r][cg * 4 + 2] = v.z; tile[r][cg * 4 + 3] = v.w;
    }
    __syncthreads();
#pragma unroll
    for (int i = 0; i < 4; ++i) {
        int lin = tid + i * 256;
        int n = lin >> 4, kg = lin & 15;
        bf16 h[4];
        h[0] = __float2bfloat16(tile[kg * 4 + 0][n]);
        h[1] = __float2bfloat16(tile[kg * 4 + 1][n]);
        h[2] = __float2bfloat16(tile[kg * 4 + 2][n]);
        h[3] = __float2bfloat16(tile[kg * 4 + 3][n]);
        *reinterpret_cast<uint2*>(&oute[(size_t)(c0 + n) * R + r0 + kg * 4]) =
            *reinterpret_cast<uint2*>(h);
    }
}

__global__ __launch_bounds__(256) void router_kernel(const float* __restrict__ x,
        const float* __restrict__ rw, const float* __restrict__ rb,
        int* __restrict__ e0a, int* __restrict__ e1a,
        float* __restrict__ w0a, float* __restrict__ w1a, int* __restrict__ counts) {
    int wid = threadIdx.x >> 6, lane = threadIdx.x & 63;
    int t = blockIdx.x * 4 + wid;
    const float* xp = x + (size_t)t * HD + lane * 16;
    float xv[16];
#pragma unroll
    for (int j = 0; j < 4; ++j) {
        float4 v = *reinterpret_cast<const float4*>(&xp[j * 4]);
        xv[4 * j] = v.x; xv[4 * j + 1] = v.y; xv[4 * j + 2] = v.z; xv[4 * j + 3] = v.w;
    }
    float acc[8] = {0.f, 0.f, 0.f, 0.f, 0.f, 0.f, 0.f, 0.f};
    const float* rp = rw + (size_t)(lane * 16) * NE;
#pragma unroll
    for (int hh = 0; hh < 16; ++hh) {
        float4 r0 = *reinterpret_cast<const float4*>(&rp[hh * 8]);
        float4 r1 = *reinterpret_cast<const float4*>(&rp[hh * 8 + 4]);
        acc[0] += xv[hh] * r0.x; acc[1] += xv[hh] * r0.y;
        acc[2] += xv[hh] * r0.z; acc[3] += xv[hh] * r0.w;
        acc[4] += xv[hh] * r1.x; acc[5] += xv[hh] * r1.y;
        acc[6] += xv[hh] * r1.z; acc[7] += xv[hh] * r1.w;
    }
#pragma unroll
    for (int e = 0; e < 8; ++e) {
#pragma unroll
        for (int off = 32; off > 0; off >>= 1) acc[e] += __shfl_xor(acc[e], off, 64);
    }
    if (lane == 0) {
        float lg[8];
#pragma unroll
        for (int e = 0; e < 8; ++e) lg[e] = acc[e] + rb[e];
        int a = 0;
#pragma unroll
        for (int e = 1; e < 8; ++e) if (lg[e] > lg[a]) a = e;
        int b = (a == 0) ? 1 : 0;
#pragma unroll
        for (int e = 0; e < 8; ++e) if (e != a && e != b && lg[e] > lg[b]) b = e;
        float wa = 1.0f / (1.0f + expf(lg[b] - lg[a]));
        float wb = 1.0f / (1.0f + expf(lg[a] - lg[b]));
        e0a[t] = a; e1a[t] = b; w0a[t] = wa; w1a[t] = wb;
        atomicAdd(&counts[a], 1);
        atomicAdd(&counts[b], 1);
    }
}

// builds offsets, cursors, and the compact 256-row M-tile map (row0, expert)
__global__ void scan_offsets_kernel(const int* __restrict__ counts, int* __restrict__ offs,
        int* __restrict__ cursor, int* __restrict__ tmr, int* __restrict__ tme,
        int* __restrict__ tmn) {
    if (threadIdx.x == 0 && blockIdx.x == 0) {
        int s = 0, nt = 0;
        for (int e = 0; e < NE; ++e) {
            offs[e] = s; cursor[e] = s;
            int c = counts[e];
            for (int j = 0; j < c; j += 256) { tmr[nt] = s + j; tme[nt] = e; ++nt; }
            s += c;
        }
        offs[NE] = s;
        tmn[0] = nt;
        for (int i = nt; i < TMAX; ++i) { tmr[i] = 0; tme[i] = 0; }
    }
}

__global__ __launch_bounds__(256) void scatter_kernel(const int* __restrict__ e0a, const int* __restrict__ e1a,
        const float* __restrict__ w0a, const float* __restrict__ w1a,
        int* __restrict__ cursor, int* __restrict__ tid_arr, float* __restrict__ tw_arr,
        int* __restrict__ slot0, int* __restrict__ slot1) {
    int t = blockIdx.x * 256 + threadIdx.x;
    int s0 = atomicAdd(&cursor[e0a[t]], 1);
    tid_arr[s0] = t; tw_arr[s0] = w0a[t]; slot0[t] = s0;
    int s1 = atomicAdd(&cursor[e1a[t]], 1);
    tid_arr[s1] = t; tw_arr[s1] = w1a[t]; slot1[t] = s1;
}

// ---- shared macros for the 4-phase 256x256 BK=64 schedule ----
#define STG_A(H, KT) do { int _d = (KT) & 1; int _ko = (KT) * 64; \
    gload_lds16(pA[H][0] + _ko, &As[_d][H][sd0]); \
    gload_lds16(pA[H][1] + _ko, &As[_d][H][sd1]); } while (0)
#define STG_B(H, KT) do { int _d = (KT) & 1; int _ko = (KT) * 64; \
    gload_lds16(pB[H][0] + _ko, &Bs[_d][H][sd0]); \
    gload_lds16(pB[H][1] + _ko, &Bs[_d][H][sd1]); } while (0)
#define RD_A(H, D) do { _Pragma("unroll") for (int mi = 0; mi < 4; ++mi) { \
    af[mi][0] = *reinterpret_cast<const s16x8*>(&As[D][H][(rab + mi * 16) * 64 + koff0]); \
    af[mi][1] = *reinterpret_cast<const s16x8*>(&As[D][H][(rab + mi * 16) * 64 + koff1]); } } while (0)
#define RD_B(H, D) do { _Pragma("unroll") for (int ni = 0; ni < 2; ++ni) { \
    bfr[ni][0] = *reinterpret_cast<const s16x8*>(&Bs[D][H][(cbb + ni * 16) * 64 + koff0]); \
    bfr[ni][1] = *reinterpret_cast<const s16x8*>(&Bs[D][H][(cbb + ni * 16) * 64 + koff1]); } } while (0)
#define MFMA_Q(MH, NH) do { _Pragma("unroll") for (int mi = 0; mi < 4; ++mi) \
    _Pragma("unroll") for (int ni = 0; ni < 2; ++ni) \
    _Pragma("unroll") for (int ks = 0; ks < 2; ++ks) \
      acc[(MH)*4+mi][(NH)*2+ni] = __builtin_amdgcn_mfma_f32_16x16x32_bf16( \
          af[mi][ks], bfr[ni][ks], acc[(MH)*4+mi][(NH)*2+ni], 0, 0, 0); } while (0)
#define PH_MID() \
    __builtin_amdgcn_s_barrier(); \
    asm volatile("s_waitcnt lgkmcnt(0)" ::: "memory"); \
    __builtin_amdgcn_sched_barrier(0); \
    __builtin_amdgcn_s_setprio(1);
#define PH_END_W() \
    __builtin_amdgcn_s_setprio(0); \
    __builtin_amdgcn_sched_barrier(0); \
    asm volatile("s_waitcnt vmcnt(4)" ::: "memory"); \
    __builtin_amdgcn_s_barrier();
#define PH_END_NW() \
    __builtin_amdgcn_s_setprio(0); \
    __builtin_amdgcn_sched_barrier(0); \
    __builtin_amdgcn_s_barrier();

// GEMM1: hmid[slot,:] = gelu( x[tok[slot],:] @ w1t[e]^T + b1[e] ), bf16 out
__global__ __launch_bounds__(512, 2) void gemm1_kernel(const bf16* __restrict__ xbf,
        const bf16* __restrict__ w1t, const float* __restrict__ b1,
        const int* __restrict__ offs, const int* __restrict__ tid_arr,
        bf16* __restrict__ hmid, const int* __restrict__ tmr,
        const int* __restrict__ tme, const int* __restrict__ tmn) {
    __shared__ bf16 As[2][2][8192];   // [dbuf][half][128 rows x 64 k]
    __shared__ bf16 Bs[2][2][8192];
    __shared__ int toks[256];
    int nwg = gridDim.x;              // 1152, %8==0
    int orig = blockIdx.x;
    int wg = (orig & 7) * (nwg >> 3) + (orig >> 3);
    int nt = wg / TMAX, tidx = wg % TMAX;
    if (tidx >= tmn[0]) return;
    int e = tme[tidx], row0 = tmr[tidx], s1 = offs[e + 1];
    int n0 = nt * 256;
    int t = threadIdx.x;
    if (t < 256) { int s = row0 + t; toks[t] = tid_arr[(s < s1) ? s : (s1 - 1)]; }
    __syncthreads();
    int lane = t & 63, w = t >> 6;
    int wr = w >> 2, wc = w & 3;                 // 2M x 4N waves, per-wave 128x64
    int lr = lane & 15, kg = lane >> 4;
    int rab = 64 * wr + lr;                      // local A row base (within half)
    int cbb = 32 * wc + lr;                      // local B row base (within half)
    int koff0 = (kg * 8) ^ ((lr & 7) << 3);      // swizzled k-offsets (elems)
    int koff1 = (32 + kg * 8) ^ ((lr & 7) << 3);
    // staging: thread covers (row rstage [+64 for j=1], src octet pre-swizzled)
    int l3 = lane >> 3, oct = lane & 7;
    int rstage = w * 8 + l3;
    int socts = (oct ^ l3) * 8;
    const bf16* w1e = w1t + (size_t)e * FHD * HD;
    const bf16* pA[2][2]; const bf16* pB[2][2];
#pragma unroll
    for (int h = 0; h < 2; ++h)
#pragma unroll
        for (int j = 0; j < 2; ++j) {
            int gr = j * 128 + h * 64 + rstage;                    // local tile row
            pA[h][j] = xbf + (size_t)toks[gr] * HD + socts;
            int cb = rstage + j * 64;
            int col = ((cb >> 5) << 6) + h * 32 + (cb & 31);       // local tile col
            pB[h][j] = w1e + (size_t)(n0 + col) * HD + socts;
        }
    int sd0 = rstage * 64 + oct * 8;             // LDS dest (elems): base + lane*16B
    int sd1 = sd0 + 4096;
    f32x4 acc[8][4] = {};
    s16x8 af[4][2], bfr[2][2];
    // prologue: stage tile0 as A0,B0,B1,A1 (8 loads), wait oldest 4
    STG_A(0, 0); STG_B(0, 0); STG_B(1, 0); STG_A(1, 0);
    asm volatile("s_waitcnt vmcnt(4)" ::: "memory");
    __builtin_amdgcn_s_barrier();
    for (int kt = 0; kt < HD / 64; ++kt) {
        int d = kt & 1, kn = kt + 1;
        // phase 0: q(0,0); stage A0(kn)
        RD_A(0, d); RD_B(0, d);
        STG_A(0, kn);
        PH_MID(); MFMA_Q(0, 0); PH_END_W();
        // phase 1: q(0,1); stage B0(kn)
        RD_B(1, d);
        STG_B(0, kn);
        PH_MID(); MFMA_Q(0, 1); PH_END_W();
        // phase 2: q(1,1); stage B1(kn)
        RD_A(1, d);
        STG_B(1, kn);
        PH_MID(); MFMA_Q(1, 1); PH_END_NW();
        // phase 3: q(1,0); stage A1(kn)
        RD_B(0, d);
        STG_A(1, kn);
        PH_MID(); MFMA_Q(1, 0); PH_END_W();
    }
#pragma unroll
    for (int m8 = 0; m8 < 8; ++m8) {
#pragma unroll
        for (int ni = 0; ni < 4; ++ni) {
            int col = n0 + wc * 64 + ni * 16 + lr;
            float bv = b1[(size_t)e * FHD + col];
#pragma unroll
            for (int r = 0; r < 4; ++r) {
                int row = wr * 128 + m8 * 16 + kg * 4 + r;
                int slot = row0 + row;
                if (slot < s1) {
                    float v2 = acc[m8][ni][r] + bv;
                    v2 = 0.5f * v2 * (1.0f + erff(v2 * 0.70710678118f));
                    hmid[(size_t)slot * FHD + col] = __float2bfloat16(v2);
                }
            }
        }
    }
}

// GEMM2 (split-K=2): ysp[slot,:] = hmid[slot, kb:kb+2048] @ w2t[e][:, kb:kb+2048]^T (+b2 for ks=0)
__global__ __launch_bounds__(512, 2) void gemm2_kernel(const bf16* __restrict__ hmid,
        const bf16* __restrict__ w2t, const float* __restrict__ b2,
        const int* __restrict__ offs, float* __restrict__ ysA, float* __restrict__ ysB,
        const int* __restrict__ tmr, const int* __restrict__ tme, const int* __restrict__ tmn) {
    __shared__ bf16 As[2][2][8192];
    __shared__ bf16 Bs[2][2][8192];
    int nwg = gridDim.x;              // 576, %8==0
    int orig = blockIdx.x;
    int wg = (orig & 7) * (nwg >> 3) + (orig >> 3);
    int gq = wg / TMAX, tidx = wg % TMAX;
    if (tidx >= tmn[0]) return;
    int ks = gq >> 2, nt = gq & 3;
    int e = tme[tidx], row0 = tmr[tidx], s1 = offs[e + 1];
    int n0 = nt * 256;
    int kb = ks * 2048;
    int t = threadIdx.x;
    int lane = t & 63, w = t >> 6;
    int wr = w >> 2, wc = w & 3;
    int lr = lane & 15, kg = lane >> 4;
    int rab = 64 * wr + lr;
    int cbb = 32 * wc + lr;
    int koff0 = (kg * 8) ^ ((lr & 7) << 3);
    int koff1 = (32 + kg * 8) ^ ((lr & 7) << 3);
    int l3 = lane >> 3, oct = lane & 7;
    int rstage = w * 8 + l3;
    int socts = (oct ^ l3) * 8;
    const bf16* w2e = w2t + (size_t)e * HD * FHD;
    const bf16* pA[2][2]; const bf16* pB[2][2];
#pragma unroll
    for (int h = 0; h < 2; ++h)
#pragma unroll
        for (int j = 0; j < 2; ++j) {
            int ar = row0 + j * 128 + h * 64 + rstage;
            if (ar >= s1) ar = s1 - 1;
            pA[h][j] = hmid + (size_t)ar * FHD + kb + socts;
            int cb = rstage + j * 64;
            int col = ((cb >> 5) << 6) + h * 32 + (cb & 31);
            pB[h][j] = w2e + (size_t)(n0 + col) * FHD + kb + socts;
        }
    int sd0 = rstage * 64 + oct * 8;
    int sd1 = sd0 + 4096;
    f32x4 acc[8][4] = {};
    s16x8 af[4][2], bfr[2][2];
    STG_A(0, 0); STG_B(0, 0); STG_B(1, 0); STG_A(1, 0);
    asm volatile("s_waitcnt vmcnt(4)" ::: "memory");
    __builtin_amdgcn_s_barrier();
    for (int kt = 0; kt < 2048 / 64; ++kt) {
        int d = kt & 1, kn = kt + 1;
        RD_A(0, d); RD_B(0, d);
        STG_A(0, kn);
        PH_MID(); MFMA_Q(0, 0); PH_END_W();
        RD_B(1, d);
        STG_B(0, kn);
        PH_MID(); MFMA_Q(0, 1); PH_END_W();
        RD_A(1, d);
        STG_B(1, kn);
        PH_MID(); MFMA_Q(1, 1); PH_END_NW();
        RD_B(0, d);
        STG_A(1, kn);
        PH_MID(); MFMA_Q(1, 0); PH_END_W();
    }
    float* ysp = ks ? ysB : ysA;
#pragma unroll
    for (int m8 = 0; m8 < 8; ++m8) {
#pragma unroll
        for (int ni = 0; ni < 4; ++ni) {
            int col = n0 + wc * 64 + ni * 16 + lr;
            float bv = ks ? 0.0f : b2[(size_t)e * HD + col];
#pragma unroll
            for (int r = 0; r < 4; ++r) {
                int row = wr * 128 + m8 * 16 + kg * 4 + r;
                int slot = row0 + row;
                if (slot < s1) ysp[(size_t)slot * HD + col] = acc[m8][ni][r] + bv;
            }
        }
    }
}

// out[t,:] = tw[s0]*(ysA[s0]+ysB[s0]) + tw[s1]*(ysA[s1]+ysB[s1])
__global__ __launch_bounds__(256) void combine_kernel(const float* __restrict__ ysA,
        const float* __restrict__ ysB,
        const int* __restrict__ slot0, const int* __restrict__ slot1,
        const float* __restrict__ tw, float* __restrict__ out) {
    int t = blockIdx.x;
    int c = threadIdx.x * 4;
    int sa = slot0[t], sb = slot1[t];
    float wa = tw[sa], wb = tw[sb];
    float4 a0 = *reinterpret_cast<const float4*>(&ysA[(size_t)sa * HD + c]);
    float4 a1 = *reinterpret_cast<const float4*>(&ysB[(size_t)sa * HD + c]);
    float4 b0 = *reinterpret_cast<const float4*>(&ysA[(size_t)sb * HD + c]);
    float4 b1 = *reinterpret_cast<const float4*>(&ysB[(size_t)sb * HD + c]);
    float4 o;
    o.x = wa * (a0.x + a1.x) + wb * (b0.x + b1.x);
    o.y = wa * (a0.y + a1.y) + wb * (b0.y + b1.y);
    o.z = wa * (a0.z + a1.z) + wb * (b0.z + b1.z);
    o.w = wa * (a0.w + a1.w) + wb * (b0.w + b1.w);
    *reinterpret_cast<float4*>(&out[(size_t)t * HD + c]) = o;
}

extern "C" void kernel_launch(void* const* d_in, const int* in_sizes, int n_in,
                              void* d_out, int out_size, void* d_ws, size_t ws_size,
                              hipStream_t stream) {
    const float* x  = (const float*)d_in[0];
    const float* rw = (const float*)d_in[1];
    const float* rb = (const float*)d_in[2];
    const float* w1 = (const float*)d_in[3];
    const float* b1 = (const float*)d_in[4];
    const float* w2 = (const float*)d_in[5];
    const float* b2 = (const float*)d_in[6];
    float* out = (float*)d_out;
    char* ws = (char*)d_ws;

    int*   counts  = (int*)(ws + OFF_COUNTS);
    int*   cursor  = (int*)(ws + OFF_CURSOR);
    int*   offs    = (int*)(ws + OFF_OFFS);
    int*   e0a     = (int*)(ws + OFF_E0);
    int*   e1a     = (int*)(ws + OFF_E1);
    float* w0a     = (float*)(ws + OFF_W0);
    float* w1a     = (float*)(ws + OFF_W1);
    int*   slot0   = (int*)(ws + OFF_S0);
    int*   slot1   = (int*)(ws + OFF_S1);
    int*   tid_arr = (int*)(ws + OFF_TID);
    float* tw_arr  = (float*)(ws + OFF_TW);
    int*   tmr     = (int*)(ws + OFF_TMR);
    int*   tme     = (int*)(ws + OFF_TME);
    int*   tmn     = (int*)(ws + OFF_TMN);
    bf16*  xbf     = (bf16*)(ws + OFF_XBF);
    bf16*  w1t     = (bf16*)(ws + OFF_W1T);
    bf16*  w2t     = (bf16*)(ws + OFF_W2T);
    bf16*  hmid    = (bf16*)(ws + OFF_HMID);
    float* ysA     = (float*)(ws + OFF_YS);
    float* ysB     = (float*)(ws + OFF_W1T);   // w1t is dead after gemm1

    hipMemsetAsync(counts, 0, 64, stream);

    cast_x_kernel<<<TT * HD / 2048, 256, 0, stream>>>(x, xbf);
    transpose_cast_kernel<<<NE * (HD / 64) * (FHD / 64), 256, 0, stream>>>(w1, w1t, HD, FHD);
    transpose_cast_kernel<<<NE * (FHD / 64) * (HD / 64), 256, 0, stream>>>(w2, w2t, FHD, HD);
    router_kernel<<<TT / 4, 256, 0, stream>>>(x, rw, rb, e0a, e1a, w0a, w1a, counts);
    scan_offsets_kernel<<<1, 64, 0, stream>>>(counts, offs, cursor, tmr, tme, tmn);
    scatter_kernel<<<TT / 256, 256, 0, stream>>>(e0a, e1a, w0a, w1a, cursor, tid_arr, tw_arr, slot0, slot1);
    gemm1_kernel<<<(FHD / 256) * TMAX, 512, 0, stream>>>(xbf, w1t, b1, offs, tid_arr, hmid, tmr, tme, tmn);
    gemm2_kernel<<<2 * (HD / 256) * TMAX, 512, 0, stream>>>(hmid, w2t, b2, offs, ysA, ysB, tmr, tme, tmn);
    combine_kernel<<<TT, 256, 0, stream>>>(ysA, ysB, slot0, slot1, tw_arr, out);
}